// Round 3
// baseline (376.034 us; speedup 1.0000x reference)
//
#include <hip/hip_runtime.h>
#include <hip/hip_fp16.h>

#define BB 2
#define DX 160
#define DY 160
#define DZ 160

constexpr int    VOL        = DX * DY * DZ;          // 4,096,000
constexpr int    NVOX       = BB * VOL;              // 8,192,000
constexpr size_t PACK_BYTES = (size_t)NVOX * 16;     // 131,072,000 B
constexpr int    NPAIR      = NVOX / 2;              // 4,096,000
constexpr int    HZ         = DZ / 2;                // 80

typedef float f2v __attribute__((ext_vector_type(2)));

// ---------------------------------------------------------------------------
// Pack: for each (b,x,y,z) store the XY-QUAD at that z (4 corners x 2ch fp16
// = 16 B = one float4), quads contiguous along z. Round-3 changes:
//  - chunked XCD swizzle: hardware round-robins blocks across 8 XCDs, which
//    put y/x-neighbor blocks (which re-read the same im rows) on DIFFERENT
//    XCD L2s -> ~4x fabric re-fetch. Chunked remap keeps neighbors on one XCD.
//  - one thread packs a z-PAIR: 4x float4 loads (2 voxels each, 16B/lane)
//    instead of 8x float2; 32B coalesced store. Halves index math, doubles
//    bytes per load instruction.
// ---------------------------------------------------------------------------
__global__ __launch_bounds__(256) void pack_kernel(const float* __restrict__ im,
                                                   float4* __restrict__ pk)
{
    const int nblk  = gridDim.x;             // 16000, divisible by 8
    const int chunk = nblk >> 3;
    const int bid   = blockIdx.x;
    const int swz   = (bid & 7) * chunk + (bid >> 3);   // bijective (nblk%8==0)
    const int pair  = swz * blockDim.x + threadIdx.x;
    if (pair >= NPAIR) return;

    const int z2 = pair % HZ;
    int t = pair / HZ;
    const int y = t % DY; t /= DY;
    const int x = t % DX;
    const int b = t / DX;

    const int x1 = min(x + 1, DX - 1);
    const int y1 = min(y + 1, DY - 1);

    // one float4 = voxels (z, z+1) x 2ch at a given (b,x,y) row
    const float4* __restrict__ imf4 = (const float4*)im;
    const int r00 = ((b * DX + x ) * DY + y ) * HZ + z2;
    const int r01 = ((b * DX + x ) * DY + y1) * HZ + z2;
    const int r10 = ((b * DX + x1) * DY + y ) * HZ + z2;
    const int r11 = ((b * DX + x1) * DY + y1) * HZ + z2;

    const float4 a00 = imf4[r00];
    const float4 a01 = imf4[r01];
    const float4 a10 = imf4[r10];
    const float4 a11 = imf4[r11];

    __half2 h0[4], h1[4];
    h0[0] = __floats2half2_rn(a00.x, a00.y);   // corner (0,0), z
    h0[1] = __floats2half2_rn(a01.x, a01.y);   // (0,1)
    h0[2] = __floats2half2_rn(a10.x, a10.y);   // (1,0)
    h0[3] = __floats2half2_rn(a11.x, a11.y);   // (1,1)
    h1[0] = __floats2half2_rn(a00.z, a00.w);   // corner (0,0), z+1
    h1[1] = __floats2half2_rn(a01.z, a01.w);
    h1[2] = __floats2half2_rn(a10.z, a10.w);
    h1[3] = __floats2half2_rn(a11.z, a11.w);

    const size_t cell = (size_t)pair * 2;      // quad index of z (z = 2*z2)
    pk[cell]     = *(const float4*)h0;
    pk[cell + 1] = *(const float4*)h1;
}

// ---------------------------------------------------------------------------
// Gather: two adjacent 16B quad reads per voxel, trilinear in fp32.
// Round-3: 8 voxels/thread, all 16 pk line-loads issued before first consume
// (MLP probe: latency-bound vs fabric-BW-bound). defgrid/out non-temporal.
// ---------------------------------------------------------------------------
__device__ __forceinline__ void lerp_quads(const float4 Q0, const float4 Q1,
                                           float fx, float fy, float fz,
                                           float& rx, float& ry)
{
    union { float4 f4; __half2 h2[4]; } a, b;
    a.f4 = Q0;
    b.f4 = Q1;

    const float wx[2] = { 1.0f - fx, fx };
    const float wy[2] = { 1.0f - fy, fy };

    rx = 0.0f; ry = 0.0f;
#pragma unroll
    for (int c = 0; c < 4; ++c) {
        const float w = wx[(c >> 1) & 1] * wy[c & 1];
        const float2 v0 = __half22float2(a.h2[c]);
        const float2 v1 = __half22float2(b.h2[c]);
        rx += w * (v0.x + fz * (v1.x - v0.x));
        ry += w * (v0.y + fz * (v1.y - v0.y));
    }
}

__global__ __launch_bounds__(256) void gather_kernel(const float4* __restrict__ pk,
                                                     const float* __restrict__ defgrid,
                                                     float2* __restrict__ out)
{
    constexpr int Q = NVOX / 8;  // 1,024,000
    const int t = blockIdx.x * blockDim.x + threadIdx.x;
    if (t >= Q) return;

    float xf[8], yf[8], zf[8];
#pragma unroll
    for (int k = 0; k < 8; ++k) {
        const float* g = defgrid + (size_t)(t + k * Q) * 3;
        xf[k] = __builtin_nontemporal_load(g + 0);
        yf[k] = __builtin_nontemporal_load(g + 1);
        zf[k] = __builtin_nontemporal_load(g + 2);
    }

    int   q0[8], q1[8];
    float fx[8], fy[8], fz[8];
#pragma unroll
    for (int k = 0; k < 8; ++k) {
        const int ax = min(max((int)floorf(xf[k]), 0), DX - 1);
        const int ay = min(max((int)floorf(yf[k]), 0), DY - 1);
        const int az = min(max((int)floorf(zf[k]), 0), DZ - 1);
        const int z1 = min(az + 1, DZ - 1);
        const int b  = (k >= 4) ? 1 : 0;          // idx = t+k*Q; k<4 -> batch 0
        const int base = ((b * DX + ax) * DY + ay) * DZ;
        q0[k] = base + az;
        q1[k] = base + z1;
        fx[k] = xf[k] - (float)ax;
        fy[k] = yf[k] - (float)ay;
        fz[k] = zf[k] - (float)az;
    }

    // issue all 16 quad loads before consuming; vmcnt retires in order so the
    // first consume only waits on the oldest load.
    float4 A[8], B[8];
#pragma unroll
    for (int k = 0; k < 8; ++k) {
        A[k] = pk[q0[k]];
        B[k] = pk[q1[k]];
    }

#pragma unroll
    for (int k = 0; k < 8; ++k) {
        float rx, ry;
        lerp_quads(A[k], B[k], fx[k], fy[k], fz[k], rx, ry);
        f2v r;
        r.x = rx;
        r.y = ry;
        __builtin_nontemporal_store(r, (f2v*)(out + (size_t)(t + k * Q)));
    }
}

// ---------------------------------------------------------------------------
// Fallback direct kernel in case ws_size < PACK_BYTES.
// ---------------------------------------------------------------------------
__global__ __launch_bounds__(256) void trilerp3d_direct(
    const float* __restrict__ im,
    const float* __restrict__ defgrid,
    float*       __restrict__ out)
{
    int idx = blockIdx.x * blockDim.x + threadIdx.x;
    if (idx >= NVOX) return;

    const float x = defgrid[(size_t)idx * 3 + 0];
    const float y = defgrid[(size_t)idx * 3 + 1];
    const float z = defgrid[(size_t)idx * 3 + 2];

    const int x0u = (int)floorf(x);
    const int y0u = (int)floorf(y);
    const int z0u = (int)floorf(z);

    const int x0 = min(max(x0u, 0), DX - 1);
    const int x1 = min(max(x0u + 1, 0), DX - 1);
    const int y0 = min(max(y0u, 0), DY - 1);
    const int y1 = min(max(y0u + 1, 0), DY - 1);
    const int z0 = min(max(z0u, 0), DZ - 1);
    const int z1 = min(max(z0u + 1, 0), DZ - 1);

    const float xd = x - (float)x0;
    const float yd = y - (float)y0;
    const float zd = z - (float)z0;

    const int b    = idx / VOL;
    const int base = b * VOL;

    const float2* __restrict__ imf = (const float2*)im;

    const int px0 = base + x0 * (DY * DZ);
    const int px1 = base + x1 * (DY * DZ);
    const int oy0 = y0 * DZ;
    const int oy1 = y1 * DZ;

    const float2 Ia = imf[px0 + oy0 + z0];
    const float2 Ib = imf[px0 + oy0 + z1];
    const float2 Ic = imf[px0 + oy1 + z0];
    const float2 Id = imf[px0 + oy1 + z1];
    const float2 Ie = imf[px1 + oy0 + z0];
    const float2 If = imf[px1 + oy0 + z1];
    const float2 Ig = imf[px1 + oy1 + z0];
    const float2 Ih = imf[px1 + oy1 + z1];

    const float xm = 1.0f - xd, ym = 1.0f - yd, zm = 1.0f - zd;

    float cae_x = Ia.x * xm + Ie.x * xd;
    float cae_y = Ia.y * xm + Ie.y * xd;
    float cbf_x = Ib.x * xm + If.x * xd;
    float cbf_y = Ib.y * xm + If.y * xd;
    float ccg_x = Ic.x * xm + Ig.x * xd;
    float ccg_y = Ic.y * xm + Ig.y * xd;
    float cdh_x = Id.x * xm + Ih.x * xd;
    float cdh_y = Id.y * xm + Ih.y * xd;

    float c0_x = cae_x * ym + ccg_x * yd;
    float c0_y = cae_y * ym + ccg_y * yd;
    float c1_x = cbf_x * ym + cdh_x * yd;
    float c1_y = cbf_y * ym + cdh_y * yd;

    float2 r;
    r.x = c0_x * zm + c1_x * zd;
    r.y = c0_y * zm + c1_y * zd;
    ((float2*)out)[idx] = r;
}

extern "C" void kernel_launch(void* const* d_in, const int* in_sizes, int n_in,
                              void* d_out, int out_size, void* d_ws, size_t ws_size,
                              hipStream_t stream) {
    const float* im      = (const float*)d_in[0];
    const float* defgrid = (const float*)d_in[1];
    float*       out     = (float*)d_out;

    const int block = 256;

    if (ws_size >= PACK_BYTES) {
        float4* pk = (float4*)d_ws;
        const int gridP = NPAIR / block;                 // 16000, exact
        pack_kernel<<<gridP, block, 0, stream>>>(im, pk);
        const int gridG = (NVOX / 8 + block - 1) / block; // 4000
        gather_kernel<<<gridG, block, 0, stream>>>(pk, defgrid, (float2*)out);
    } else {
        const int grid = (NVOX + block - 1) / block;
        trilerp3d_direct<<<grid, block, 0, stream>>>(im, defgrid, out);
    }
}

// Round 4
// 371.321 us; speedup vs baseline: 1.0127x; 1.0127x over previous
//
#include <hip/hip_runtime.h>
#include <hip/hip_fp16.h>

#define BB 2
#define DX 160
#define DY 160
#define DZ 160

constexpr int    VOL        = DX * DY * DZ;          // 4,096,000
constexpr int    NVOX       = BB * VOL;              // 8,192,000
constexpr size_t PACK_BYTES = (size_t)NVOX * 16;     // 131,072,000 B
constexpr int    HZ         = DZ / 2;                // 80 z-pairs per column

typedef float f2v __attribute__((ext_vector_type(2)));

// ---------------------------------------------------------------------------
// Pack: for each (b,x,y,z) store the XY-QUAD at that z (4 corners x 2ch fp16
// = 16 B = one float4), quads contiguous along z.
//
// Round-4: 3D TILE blocks. Linear z-inner mapping put the x-halo reuse 50
// blocks (~3.3 MB of traffic) away -> missed the 4 MiB XCD L2 -> 4x read
// amplification over fabric (pack was fabric-bound at ~184 us, same ~3.6 TB/s
// operating point as gather). Each block now covers a 4x * 4y * 16zpair brick:
// halo reuse is in-block (L1) or <=200 blocks away on the same XCD (~1.6 MB
// intervening < L2), so unique-read traffic drops ~4x -> ~65-100 MB.
// ---------------------------------------------------------------------------
constexpr int TBX = 4, TBY = 4, TBZ = 16;            // 4*4*16 = 256 threads
constexpr int NBX = DX / TBX;                        // 40
constexpr int NBY = DY / TBY;                        // 40
constexpr int NBZ = HZ / TBZ;                        // 5
constexpr int PACK_BLOCKS = BB * NBX * NBY * NBZ;    // 16000 (divisible by 8)

__global__ __launch_bounds__(256) void pack_kernel(const float* __restrict__ im,
                                                   float4* __restrict__ pk)
{
    // chunked XCD swizzle: hardware round-robins blockIdx across 8 XCDs;
    // remap so each XCD owns a contiguous tile range (bijective: nblk%8==0).
    const int nblk  = gridDim.x;                     // 16000
    const int chunk = nblk >> 3;
    const int bid   = blockIdx.x;
    int t = (bid & 7) * chunk + (bid >> 3);

    const int bz = t % NBZ; t /= NBZ;                // z innermost: x/y-neighbor
    const int by = t % NBY; t /= NBY;                // tiles are 5 / 200 blocks
    const int bx = t % NBX; t /= NBX;                // apart on the same XCD
    const int b  = t;

    const int tid = threadIdx.x;
    const int tz  = tid & 15;
    const int ty  = (tid >> 4) & 3;
    const int tx  = tid >> 6;

    const int x  = bx * TBX + tx;
    const int y  = by * TBY + ty;
    const int z2 = bz * TBZ + tz;

    const int x1 = min(x + 1, DX - 1);
    const int y1 = min(y + 1, DY - 1);

    // one float4 = voxels (z, z+1) x 2ch at a given (b,x,y) row; z = 2*z2
    const float4* __restrict__ imf4 = (const float4*)im;
    const float4 a00 = imf4[((b * DX + x ) * DY + y ) * HZ + z2];
    const float4 a01 = imf4[((b * DX + x ) * DY + y1) * HZ + z2];
    const float4 a10 = imf4[((b * DX + x1) * DY + y ) * HZ + z2];
    const float4 a11 = imf4[((b * DX + x1) * DY + y1) * HZ + z2];

    __half2 h0[4], h1[4];
    h0[0] = __floats2half2_rn(a00.x, a00.y);   // corner (0,0), z
    h0[1] = __floats2half2_rn(a01.x, a01.y);   // (0,1)
    h0[2] = __floats2half2_rn(a10.x, a10.y);   // (1,0)
    h0[3] = __floats2half2_rn(a11.x, a11.y);   // (1,1)
    h1[0] = __floats2half2_rn(a00.z, a00.w);   // corner (0,0), z+1
    h1[1] = __floats2half2_rn(a01.z, a01.w);
    h1[2] = __floats2half2_rn(a10.z, a10.w);
    h1[3] = __floats2half2_rn(a11.z, a11.w);

    const size_t pair = (size_t)((b * DX + x) * DY + y) * HZ + z2;
    const size_t cell = pair * 2;              // quad index of z = 2*z2
    pk[cell]     = *(const float4*)h0;         // cached: want L3 residency
    pk[cell + 1] = *(const float4*)h1;
}

// ---------------------------------------------------------------------------
// Gather (round-2 version — best measured): two adjacent 16B quad reads per
// voxel, trilinear in fp32, 4 voxels/thread. Pinned at ~3.6 TB/s random-line
// fabric rate (r1/r2/r3 all equal); defgrid/out non-temporal streams.
// ---------------------------------------------------------------------------
__device__ __forceinline__ void lerp_quads(const float4 Q0, const float4 Q1,
                                           float fx, float fy, float fz,
                                           float& rx, float& ry)
{
    union { float4 f4; __half2 h2[4]; } a, b;
    a.f4 = Q0;
    b.f4 = Q1;

    const float wx[2] = { 1.0f - fx, fx };
    const float wy[2] = { 1.0f - fy, fy };

    rx = 0.0f; ry = 0.0f;
#pragma unroll
    for (int c = 0; c < 4; ++c) {
        const float w = wx[(c >> 1) & 1] * wy[c & 1];
        const float2 v0 = __half22float2(a.h2[c]);
        const float2 v1 = __half22float2(b.h2[c]);
        rx += w * (v0.x + fz * (v1.x - v0.x));
        ry += w * (v0.y + fz * (v1.y - v0.y));
    }
}

__global__ __launch_bounds__(256) void gather_kernel(const float4* __restrict__ pk,
                                                     const float* __restrict__ defgrid,
                                                     float2* __restrict__ out)
{
    constexpr int Q = NVOX / 4;  // 2,048,000
    const int t = blockIdx.x * blockDim.x + threadIdx.x;
    if (t >= Q) return;

    int   idx[4];
    float xf[4], yf[4], zf[4];
#pragma unroll
    for (int k = 0; k < 4; ++k) {
        idx[k] = t + k * Q;
        const float* g = defgrid + (size_t)idx[k] * 3;
        xf[k] = __builtin_nontemporal_load(g + 0);
        yf[k] = __builtin_nontemporal_load(g + 1);
        zf[k] = __builtin_nontemporal_load(g + 2);
    }

    size_t q0[4], q1[4];
    float  fx[4], fy[4], fz[4];
#pragma unroll
    for (int k = 0; k < 4; ++k) {
        const int ax = min(max((int)floorf(xf[k]), 0), DX - 1);
        const int ay = min(max((int)floorf(yf[k]), 0), DY - 1);
        const int az = min(max((int)floorf(zf[k]), 0), DZ - 1);
        const int z1 = min(az + 1, DZ - 1);
        const int b  = (idx[k] >= VOL) ? 1 : 0;
        const size_t base = (size_t)(((b * DX + ax) * DY + ay)) * DZ;
        q0[k] = base + az;
        q1[k] = base + z1;
        fx[k] = xf[k] - (float)ax;
        fy[k] = yf[k] - (float)ay;
        fz[k] = zf[k] - (float)az;
    }

    // issue all 8 quad loads before consuming
    float4 A[4], B[4];
#pragma unroll
    for (int k = 0; k < 4; ++k) {
        A[k] = pk[q0[k]];
        B[k] = pk[q1[k]];
    }

#pragma unroll
    for (int k = 0; k < 4; ++k) {
        float rx, ry;
        lerp_quads(A[k], B[k], fx[k], fy[k], fz[k], rx, ry);
        f2v r;
        r.x = rx;
        r.y = ry;
        __builtin_nontemporal_store(r, (f2v*)(out + idx[k]));
    }
}

// ---------------------------------------------------------------------------
// Fallback direct kernel in case ws_size < PACK_BYTES.
// ---------------------------------------------------------------------------
__global__ __launch_bounds__(256) void trilerp3d_direct(
    const float* __restrict__ im,
    const float* __restrict__ defgrid,
    float*       __restrict__ out)
{
    int idx = blockIdx.x * blockDim.x + threadIdx.x;
    if (idx >= NVOX) return;

    const float x = defgrid[(size_t)idx * 3 + 0];
    const float y = defgrid[(size_t)idx * 3 + 1];
    const float z = defgrid[(size_t)idx * 3 + 2];

    const int x0u = (int)floorf(x);
    const int y0u = (int)floorf(y);
    const int z0u = (int)floorf(z);

    const int x0 = min(max(x0u, 0), DX - 1);
    const int x1 = min(max(x0u + 1, 0), DX - 1);
    const int y0 = min(max(y0u, 0), DY - 1);
    const int y1 = min(max(y0u + 1, 0), DY - 1);
    const int z0 = min(max(z0u, 0), DZ - 1);
    const int z1 = min(max(z0u + 1, 0), DZ - 1);

    const float xd = x - (float)x0;
    const float yd = y - (float)y0;
    const float zd = z - (float)z0;

    const int b    = idx / VOL;
    const int base = b * VOL;

    const float2* __restrict__ imf = (const float2*)im;

    const int px0 = base + x0 * (DY * DZ);
    const int px1 = base + x1 * (DY * DZ);
    const int oy0 = y0 * DZ;
    const int oy1 = y1 * DZ;

    const float2 Ia = imf[px0 + oy0 + z0];
    const float2 Ib = imf[px0 + oy0 + z1];
    const float2 Ic = imf[px0 + oy1 + z0];
    const float2 Id = imf[px0 + oy1 + z1];
    const float2 Ie = imf[px1 + oy0 + z0];
    const float2 If = imf[px1 + oy0 + z1];
    const float2 Ig = imf[px1 + oy1 + z0];
    const float2 Ih = imf[px1 + oy1 + z1];

    const float xm = 1.0f - xd, ym = 1.0f - yd, zm = 1.0f - zd;

    float cae_x = Ia.x * xm + Ie.x * xd;
    float cae_y = Ia.y * xm + Ie.y * xd;
    float cbf_x = Ib.x * xm + If.x * xd;
    float cbf_y = Ib.y * xm + If.y * xd;
    float ccg_x = Ic.x * xm + Ig.x * xd;
    float ccg_y = Ic.y * xm + Ig.y * xd;
    float cdh_x = Id.x * xm + Ih.x * xd;
    float cdh_y = Id.y * xm + Ih.y * xd;

    float c0_x = cae_x * ym + ccg_x * yd;
    float c0_y = cae_y * ym + ccg_y * yd;
    float c1_x = cbf_x * ym + cdh_x * yd;
    float c1_y = cbf_y * ym + cdh_y * yd;

    float2 r;
    r.x = c0_x * zm + c1_x * zd;
    r.y = c0_y * zm + c1_y * zd;
    ((float2*)out)[idx] = r;
}

extern "C" void kernel_launch(void* const* d_in, const int* in_sizes, int n_in,
                              void* d_out, int out_size, void* d_ws, size_t ws_size,
                              hipStream_t stream) {
    const float* im      = (const float*)d_in[0];
    const float* defgrid = (const float*)d_in[1];
    float*       out     = (float*)d_out;

    const int block = 256;

    if (ws_size >= PACK_BYTES) {
        float4* pk = (float4*)d_ws;
        pack_kernel<<<PACK_BLOCKS, block, 0, stream>>>(im, pk);
        const int gridG = (NVOX / 4 + block - 1) / block;  // 8000
        gather_kernel<<<gridG, block, 0, stream>>>(pk, defgrid, (float2*)out);
    } else {
        const int grid = (NVOX + block - 1) / block;
        trilerp3d_direct<<<grid, block, 0, stream>>>(im, defgrid, out);
    }
}